// Round 3
// baseline (320.075 us; speedup 1.0000x reference)
//
#include <hip/hip_runtime.h>
#include <hip/hip_bf16.h>

#define NB 32
#define NC 256
#define NH 64
#define NW 64

typedef unsigned short u16;

// ---- intermediates in static device globals (no dependence on ws_size) ----
__device__ int   g_mode;                    // 1 = bf16 inputs/outputs, 0 = f32
__device__ float g_cmean[NB * 4096];        // mean over C of x  [b][h*64+w]
__device__ float g_catT[NB * 128 * NC];     // cat transposed    [b][l][c]
__device__ float g_fch[NB * NC];
__device__ float g_fsa[NB * 4096];
__device__ float g_sh[NB * NC * 64];
__device__ float g_sw[NB * NC * 64];

__device__ __forceinline__ float bf2f(unsigned int u) {
    union { unsigned int i; float f; } v; v.i = u << 16; return v.f;
}
__device__ __forceinline__ u16 f2bf(float f) {
    union { float f; unsigned int i; } v; v.f = f;
    unsigned int i = v.i;
    unsigned int r = (i + 0x7fffu + ((i >> 16) & 1u)) >> 16;   // RNE
    return (u16)r;
}
__device__ __forceinline__ float sigmoidf_(float x) {
    return 1.f / (1.f + expf(-x));
}

// load 8 consecutive x elements starting at element index i8*8
__device__ __forceinline__ void loadx8(const void* x, size_t i8, int mode, float* v) {
    if (mode) {
        const uint4 u = ((const uint4*)x)[i8];
        v[0] = bf2f(u.x & 0xffffu); v[1] = bf2f(u.x >> 16);
        v[2] = bf2f(u.y & 0xffffu); v[3] = bf2f(u.y >> 16);
        v[4] = bf2f(u.z & 0xffffu); v[5] = bf2f(u.z >> 16);
        v[6] = bf2f(u.w & 0xffffu); v[7] = bf2f(u.w >> 16);
    } else {
        const float4 a = ((const float4*)x)[i8 * 2];
        const float4 b = ((const float4*)x)[i8 * 2 + 1];
        v[0] = a.x; v[1] = a.y; v[2] = a.z; v[3] = a.w;
        v[4] = b.x; v[5] = b.y; v[6] = b.z; v[7] = b.w;
    }
}
__device__ __forceinline__ float loadw(const void* p, int i, int mode) {
    return mode ? bf2f((unsigned int)((const u16*)p)[i]) : ((const float*)p)[i];
}
__device__ __forceinline__ void store8(void* o, size_t i8, int mode, const float* v) {
    if (mode) {
        uint4 u;
        u.x = (unsigned int)f2bf(v[0]) | ((unsigned int)f2bf(v[1]) << 16);
        u.y = (unsigned int)f2bf(v[2]) | ((unsigned int)f2bf(v[3]) << 16);
        u.z = (unsigned int)f2bf(v[4]) | ((unsigned int)f2bf(v[5]) << 16);
        u.w = (unsigned int)f2bf(v[6]) | ((unsigned int)f2bf(v[7]) << 16);
        ((uint4*)o)[i8] = u;
    } else {
        ((float4*)o)[i8 * 2]     = make_float4(v[0], v[1], v[2], v[3]);
        ((float4*)o)[i8 * 2 + 1] = make_float4(v[4], v[5], v[6], v[7]);
    }
}

// ---------------------------------------------------------------------------
// kSniff: decide input dtype. If x is f32, even-indexed u16s are random
// mantissa bits (~32% land in a plausible exponent window); if bf16, ~100%.
// ---------------------------------------------------------------------------
__global__ __launch_bounds__(256) void kSniff(const u16* __restrict__ xr) {
    __shared__ int cnt;
    if (threadIdx.x == 0) cnt = 0;
    __syncthreads();
    int local = 0;
#pragma unroll
    for (int i = 0; i < 8; ++i) {
        const u16 w = xr[(threadIdx.x * 8 + i) * 2];   // even u16 indices
        const unsigned e = (w >> 7) & 0xffu;
        if (w == 0 || (e >= 0x40u && e <= 0x90u)) ++local;
    }
    atomicAdd(&cnt, local);
    __syncthreads();
    if (threadIdx.x == 0) g_mode = (cnt >= 1536) ? 1 : 0;   // >=75% of 2048
}

__global__ __launch_bounds__(256) void kZero() {
    const int j = (blockIdx.x * 256 + threadIdx.x) * 4;
    *(float4*)(g_cmean + j) = make_float4(0.f, 0.f, 0.f, 0.f);
}

// ---------------------------------------------------------------------------
// Kernel A: per (b, 16-channel group) — row means, col means (-> catT
// [b][l][c]), channel-mean accumulation via LDS + global atomicAdd.
// ---------------------------------------------------------------------------
__global__ __launch_bounds__(256) void kA(const void* __restrict__ x) {
    __shared__ float cmean_lds[4096];
    __shared__ __align__(16) float plane_f[4096];
    __shared__ float rowsum[16 * 64];
    __shared__ float colsum[16 * 64];
    __shared__ float colpart[256];

    const int t  = threadIdx.x;
    const int cg = blockIdx.x;   // 0..15
    const int b  = blockIdx.y;   // 0..31
    const int mode = g_mode;

    for (int j = t; j < 4096; j += 256) cmean_lds[j] = 0.f;
    __syncthreads();

    for (int ch = 0; ch < 16; ++ch) {
        const int c = cg * 16 + ch;
        const size_t plane_i8 = ((size_t)(b * NC + c)) << 9;   // plane/8
#pragma unroll
        for (int i = 0; i < 2; ++i) {
            const int j = i * 2048 + t * 8;
            float v[8];
            loadx8(x, plane_i8 + (j >> 3), mode, v);
            *(float4*)(plane_f + j)     = make_float4(v[0], v[1], v[2], v[3]);
            *(float4*)(plane_f + j + 4) = make_float4(v[4], v[5], v[6], v[7]);
            // channel-sum: fixed per-thread ownership of positions -> no race
            cmean_lds[j + 0] += v[0]; cmean_lds[j + 1] += v[1];
            cmean_lds[j + 2] += v[2]; cmean_lds[j + 3] += v[3];
            cmean_lds[j + 4] += v[4]; cmean_lds[j + 5] += v[5];
            cmean_lds[j + 6] += v[6]; cmean_lds[j + 7] += v[7];
            // row sum: row h = j/64 covered by this 8-lane group
            float s = ((v[0] + v[1]) + (v[2] + v[3])) + ((v[4] + v[5]) + (v[6] + v[7]));
            s += __shfl_xor(s, 1);
            s += __shfl_xor(s, 2);
            s += __shfl_xor(s, 4);
            if ((t & 7) == 0) rowsum[ch * 64 + (j >> 6)] = s;
        }
        __syncthreads();
        {   // column partials: thread t handles col t%64, 16-row strip t/64
            const int col = t & 63, hr = t >> 6;
            float p = 0.f;
#pragma unroll
            for (int hh = 0; hh < 16; ++hh)
                p += plane_f[(hr * 16 + hh) * 64 + col];
            colpart[t] = p;
        }
        __syncthreads();
        if (t < 64)
            colsum[ch * 64 + t] =
                colpart[t] + colpart[64 + t] + colpart[128 + t] + colpart[192 + t];
        __syncthreads();   // protects plane_f/colpart reuse next channel
    }

    // store catT[b][l][c0..c0+15]; l<64 -> x_h (mean over W), l>=64 -> x_w
    const float inv64 = 1.f / 64.f;
    {
        const int lc = t & 15;
#pragma unroll
        for (int r = 0; r < 8; ++r) {
            const int l = r * 16 + (t >> 4);
            const float val =
                (l < 64 ? rowsum[lc * 64 + l] : colsum[lc * 64 + (l - 64)]) * inv64;
            g_catT[((size_t)(b * 128 + l)) * NC + cg * 16 + lc] = val;
        }
    }
    const float invC = 1.f / 256.f;
    for (int j = t; j < 4096; j += 256)
        atomicAdd(&g_cmean[b * 4096 + j], cmean_lds[j] * invC);
}

// ---------------------------------------------------------------------------
// Kernel B: one block per batch. pooled -> f_ch (conv1d K=5 SAME over C),
// y = w10 @ cat, BN+ReLU, s_h/s_w = sigmoid(w11 @ y), f_sa = sigmoid(conv3x3).
// ---------------------------------------------------------------------------
#define W10_STRIDE 260
__global__ __launch_bounds__(256) void kB(
    const void* __restrict__ w10, const void* __restrict__ w11,
    const void* __restrict__ bn_gamma, const void* __restrict__ bn_beta,
    const void* __restrict__ bn_mean, const void* __restrict__ bn_var,
    const void* __restrict__ w20, const void* __restrict__ w21) {

    __shared__ __align__(16) float un[48 * W10_STRIDE];
    __shared__ float y_lds[16 * 129];
    __shared__ float pooled[260];
    __shared__ float bnA[16], bnB[16], w20f[5], w21f[9];

    const int t = threadIdx.x, b = blockIdx.x;
    const int mode = g_mode;
    float* w10_lds = un;
    float* cat_lds = un + 16 * W10_STRIDE;

    for (int j = t; j < 4096; j += 256)
        w10_lds[(j >> 8) * W10_STRIDE + (j & 255)] = loadw(w10, j, mode);
    if (t < 16) {
        const float inv = rsqrtf(loadw(bn_var, t, mode) + 1e-5f) *
                          loadw(bn_gamma, t, mode);
        bnA[t] = inv;
        bnB[t] = loadw(bn_beta, t, mode) - loadw(bn_mean, t, mode) * inv;
    }
    if (t < 5) w20f[t] = loadw(w20, t, mode);
    if (t < 9) w21f[t] = loadw(w21, t, mode);
    {   // pooled[c] = mean over h of x_h  (== mean over H,W)
        float p = 0.f;
        for (int l = 0; l < 64; ++l) p += g_catT[((size_t)(b * 128 + l)) * NC + t];
        pooled[2 + t] = p * (1.f / 64.f);
    }
    if (t < 2) { pooled[t] = 0.f; pooled[258 + t] = 0.f; }
    __syncthreads();
    {   // f_ch: cross-correlation, zero-padded SAME
        float acc = 0.f;
#pragma unroll
        for (int k = 0; k < 5; ++k) acc = fmaf(w20f[k], pooled[t + k], acc);
        g_fch[b * 256 + t] = acc;
    }
    // y in quarters of 32 l-columns
    for (int q = 0; q < 4; ++q) {
        __syncthreads();
#pragma unroll
        for (int r = 0; r < 8; ++r) {
            const int idx4 = r * 256 + t;
            const int l = idx4 >> 6;
            const int c = (idx4 & 63) << 2;
            const float4 v =
                *(const float4*)(g_catT + ((size_t)(b * 128 + q * 32 + l)) * NC + c);
            *(float4*)(cat_lds + l * W10_STRIDE + c) = v;
        }
        __syncthreads();
#pragma unroll
        for (int rep = 0; rep < 2; ++rep) {
            const int o = rep * 256 + t;
            const int m = o & 15, li = o >> 4;
            const float4* wr = (const float4*)(w10_lds + m * W10_STRIDE);
            const float4* cr = (const float4*)(cat_lds + li * W10_STRIDE);
            float acc = 0.f;
#pragma unroll 8
            for (int c4 = 0; c4 < 64; ++c4) {
                const float4 a = wr[c4], v = cr[c4];
                acc = fmaf(a.x, v.x, fmaf(a.y, v.y, fmaf(a.z, v.z, fmaf(a.w, v.w, acc))));
            }
            const float yv = fmaxf(fmaf(acc, bnA[m], bnB[m]), 0.f);   // BN + ReLU
            y_lds[m * 129 + q * 32 + li] = yv;
        }
    }
    __syncthreads();
    // phase 2 staging (w10/cat regions dead)
    float* w11f = un;
    float* cm   = un + 4096;
    for (int j = t; j < 4096; j += 256) {
        w11f[j] = loadw(w11, j, mode);   // [c][m] row-major
        cm[j]   = g_cmean[b * 4096 + j];
    }
    __syncthreads();
    // s_h / s_w
    for (int it = 0; it < 64; ++it) {
        const int c  = it * 4 + (t >> 6);
        const int hw = t & 63;
        const float* wc = w11f + c * 16;
        float ah = 0.f, aw = 0.f;
#pragma unroll
        for (int m = 0; m < 16; ++m) {
            ah = fmaf(wc[m], y_lds[m * 129 + hw], ah);
            aw = fmaf(wc[m], y_lds[m * 129 + 64 + hw], aw);
        }
        g_sh[((size_t)(b * NC + c)) * 64 + hw] = sigmoidf_(ah);
        g_sw[((size_t)(b * NC + c)) * 64 + hw] = sigmoidf_(aw);
    }
    // f_sa: 3x3 zero-padded cross-correlation + sigmoid
    for (int r = 0; r < 16; ++r) {
        const int j = r * 256 + t;
        const int h = j >> 6, w = j & 63;
        float acc = 0.f;
#pragma unroll
        for (int dy = 0; dy < 3; ++dy) {
            const int hy = h + dy - 1;
            if (hy < 0 || hy > 63) continue;
#pragma unroll
            for (int dx = 0; dx < 3; ++dx) {
                const int wx = w + dx - 1;
                if (wx < 0 || wx > 63) continue;
                acc = fmaf(w21f[dy * 3 + dx], cm[hy * 64 + wx], acc);
            }
        }
        g_fsa[b * 4096 + j] = sigmoidf_(acc);
    }
}

// ---------------------------------------------------------------------------
// Kernel C: out = x * (f_ch + s_h*s_w + f_sa), 8 elements per thread.
// ---------------------------------------------------------------------------
__global__ __launch_bounds__(256) void kC(const void* __restrict__ x,
                                          void* __restrict__ out) {
    const unsigned e = blockIdx.x * 256 + threadIdx.x;   // < 2^22
    const int w0 = (e & 7) << 3;
    const int h  = (e >> 3) & 63;
    const int c  = (e >> 9) & 255;
    const int b  = e >> 17;
    const int mode = g_mode;

    float v[8];
    loadx8(x, e, mode, v);

    const float fc = g_fch[b * 256 + c];
    const float sh = g_sh[((size_t)(b * NC + c)) * 64 + h];
    const float* swp = g_sw + ((size_t)(b * NC + c)) * 64 + w0;
    const float* fsp = g_fsa + (size_t)b * 4096 + h * 64 + w0;
    const float4 swa = *(const float4*)(swp);
    const float4 swb = *(const float4*)(swp + 4);
    const float4 fsa = *(const float4*)(fsp);
    const float4 fsb = *(const float4*)(fsp + 4);

    float r[8];
    r[0] = v[0] * (fc + sh * swa.x + fsa.x);
    r[1] = v[1] * (fc + sh * swa.y + fsa.y);
    r[2] = v[2] * (fc + sh * swa.z + fsa.z);
    r[3] = v[3] * (fc + sh * swa.w + fsa.w);
    r[4] = v[4] * (fc + sh * swb.x + fsb.x);
    r[5] = v[5] * (fc + sh * swb.y + fsb.y);
    r[6] = v[6] * (fc + sh * swb.z + fsb.z);
    r[7] = v[7] * (fc + sh * swb.w + fsb.w);

    store8(out, e, mode, r);
}

extern "C" void kernel_launch(void* const* d_in, const int* in_sizes, int n_in,
                              void* d_out, int out_size, void* d_ws, size_t ws_size,
                              hipStream_t stream) {
    const void* x        = d_in[0];
    const void* w10      = d_in[1];
    const void* w11      = d_in[2];
    const void* bn_gamma = d_in[3];
    const void* bn_beta  = d_in[4];
    const void* bn_mean  = d_in[5];
    const void* bn_var   = d_in[6];
    const void* w20      = d_in[7];
    const void* w21      = d_in[8];

    kSniff<<<1, 256, 0, stream>>>((const u16*)x);
    kZero<<<(NB * 4096 / 4) / 256, 256, 0, stream>>>();
    kA<<<dim3(16, NB), 256, 0, stream>>>(x);
    kB<<<NB, 256, 0, stream>>>(w10, w11, bn_gamma, bn_beta,
                               bn_mean, bn_var, w20, w21);
    kC<<<(NB * NC * NH * NW / 8) / 256, 256, 0, stream>>>(x, d_out);
}

// Round 5
// 313.822 us; speedup vs baseline: 1.0199x; 1.0199x over previous
//
#include <hip/hip_runtime.h>
#include <hip/hip_bf16.h>

#define NB 32
#define NC 256
#define NH 64
#define NW 64

typedef unsigned short u16;

// ---- intermediates in static device globals (ws_size-independent) ----
__device__ int   g_mode;                    // 1 = bf16 inputs/outputs, 0 = f32
__device__ float g_cmeanp[NB * 16 * 4096];  // per-(b,cg) partial channel-sums (scaled 1/256)
__device__ float g_catT[NB * 128 * NC];     // cat transposed [b][l][c]
__device__ float g_fch[NB * NC];
__device__ float g_fsa[NB * 4096];
__device__ float g_sh[NB * NC * 64];
__device__ float g_sw[NB * NC * 64];

__device__ __forceinline__ float bf2f(unsigned int u) {
    union { unsigned int i; float f; } v; v.i = u << 16; return v.f;
}
__device__ __forceinline__ u16 f2bf(float f) {
    union { float f; unsigned int i; } v; v.f = f;
    unsigned int i = v.i;
    unsigned int r = (i + 0x7fffu + ((i >> 16) & 1u)) >> 16;   // RNE
    return (u16)r;
}
__device__ __forceinline__ unsigned int pack2(float a, float b) {
    return (unsigned int)f2bf(a) | ((unsigned int)f2bf(b) << 16);
}
__device__ __forceinline__ float sigmoidf_(float x) {
    return 1.f / (1.f + expf(-x));
}

// load 8 consecutive x elements starting at element index i8*8 (mode-opaque)
__device__ __forceinline__ void loadx8(const void* x, size_t i8, int mode, float* v) {
    if (mode) {
        const uint4 u = ((const uint4*)x)[i8];
        v[0] = bf2f(u.x & 0xffffu); v[1] = bf2f(u.x >> 16);
        v[2] = bf2f(u.y & 0xffffu); v[3] = bf2f(u.y >> 16);
        v[4] = bf2f(u.z & 0xffffu); v[5] = bf2f(u.z >> 16);
        v[6] = bf2f(u.w & 0xffffu); v[7] = bf2f(u.w >> 16);
    } else {
        const float4 a = ((const float4*)x)[i8 * 2];
        const float4 b = ((const float4*)x)[i8 * 2 + 1];
        v[0] = a.x; v[1] = a.y; v[2] = a.z; v[3] = a.w;
        v[4] = b.x; v[5] = b.y; v[6] = b.z; v[7] = b.w;
    }
}
__device__ __forceinline__ float loadw(const void* p, int i, int mode) {
    return mode ? bf2f((unsigned int)((const u16*)p)[i]) : ((const float*)p)[i];
}
__device__ __forceinline__ void store8(void* o, size_t i8, int mode, const float* v) {
    if (mode) {
        uint4 u;
        u.x = pack2(v[0], v[1]);
        u.y = pack2(v[2], v[3]);
        u.z = pack2(v[4], v[5]);
        u.w = pack2(v[6], v[7]);
        ((uint4*)o)[i8] = u;
    } else {
        ((float4*)o)[i8 * 2]     = make_float4(v[0], v[1], v[2], v[3]);
        ((float4*)o)[i8 * 2 + 1] = make_float4(v[4], v[5], v[6], v[7]);
    }
}

// ---------------------------------------------------------------------------
// kSniff: decide input dtype (verbatim from the passing round-3 kernel).
// ---------------------------------------------------------------------------
__global__ __launch_bounds__(256) void kSniff(const u16* __restrict__ xr) {
    __shared__ int cnt;
    if (threadIdx.x == 0) cnt = 0;
    __syncthreads();
    int local = 0;
#pragma unroll
    for (int i = 0; i < 8; ++i) {
        const u16 w = xr[(threadIdx.x * 8 + i) * 2];   // even u16 indices
        const unsigned e = (w >> 7) & 0xffu;
        if (w == 0 || (e >= 0x40u && e <= 0x90u)) ++local;
    }
    atomicAdd(&cnt, local);
    __syncthreads();
    if (threadIdx.x == 0) g_mode = (cnt >= 1536) ? 1 : 0;   // >=75% of 2048
}

// ---------------------------------------------------------------------------
// Kernel A: block = (cg, b); 4 waves, each owns 4 channels. One barrier.
// Row sums via 8-lane shfl; col sums in registers + xor-shfl; per-wave cmean
// partials packed bf16x2 in LDS (40 KB total). No atomics, no init kernel.
// ---------------------------------------------------------------------------
__global__ __launch_bounds__(256) void kA(const void* __restrict__ x) {
    __shared__ unsigned int sliceP[4][2048];   // bf16x2-packed cmean partials (32 KB)
    __shared__ float rowsum[16 * 64];          // 4 KB
    __shared__ float colsum[16 * 64];          // 4 KB

    const int t  = threadIdx.x;
    const int ln = t & 63, wv = t >> 6;
    const int cg = blockIdx.x;          // 0..15
    const int b  = blockIdx.y;          // 0..31
    const int mode = g_mode;

    float colacc[4][8];
#pragma unroll
    for (int cc = 0; cc < 4; ++cc)
#pragma unroll
        for (int k = 0; k < 8; ++k) colacc[cc][k] = 0.f;

    const int ch0 = cg * 16 + wv * 4;   // this wave's first channel
    const size_t i8base = (((size_t)(b * NC + ch0)) << 9) + ln;   // /8 units

    for (int p = 0; p < 8; ++p) {       // 8 passes of 512 elements (8 rows)
        float cme[8];
#pragma unroll
        for (int k = 0; k < 8; ++k) cme[k] = 0.f;
#pragma unroll
        for (int cc = 0; cc < 4; ++cc) {
            float v[8];
            loadx8(x, i8base + (((size_t)cc) << 9) + p * 64, mode, v);
#pragma unroll
            for (int k = 0; k < 8; ++k) {
                cme[k] += v[k];
                colacc[cc][k] += v[k];
            }
            // row sum: this 8-lane group covers row p*8 + ln/8
            float s = ((v[0] + v[1]) + (v[2] + v[3])) + ((v[4] + v[5]) + (v[6] + v[7]));
            s += __shfl_xor(s, 1);
            s += __shfl_xor(s, 2);
            s += __shfl_xor(s, 4);
            if ((ln & 7) == 0)
                rowsum[(wv * 4 + cc) * 64 + p * 8 + (ln >> 3)] = s;
        }
        // each (wave, position) slot written exactly once -> no init needed
        uint4 pk;
        pk.x = pack2(cme[0], cme[1]);
        pk.y = pack2(cme[2], cme[3]);
        pk.z = pack2(cme[4], cme[5]);
        pk.w = pack2(cme[6], cme[7]);
        *(uint4*)&sliceP[wv][p * 256 + ln * 4] = pk;
    }

    // column totals: sum over lanes differing in bits 3..5 (row-strip index)
#pragma unroll
    for (int cc = 0; cc < 4; ++cc)
#pragma unroll
        for (int k = 0; k < 8; ++k) {
            float v = colacc[cc][k];
            v += __shfl_xor(v, 8);
            v += __shfl_xor(v, 16);
            v += __shfl_xor(v, 32);
            colacc[cc][k] = v;
        }
    if (ln < 8) {                       // lane ln holds cols ln*8 .. ln*8+7
#pragma unroll
        for (int cc = 0; cc < 4; ++cc) {
            *(float4*)&colsum[(wv * 4 + cc) * 64 + ln * 8] =
                make_float4(colacc[cc][0], colacc[cc][1], colacc[cc][2], colacc[cc][3]);
            *(float4*)&colsum[(wv * 4 + cc) * 64 + ln * 8 + 4] =
                make_float4(colacc[cc][4], colacc[cc][5], colacc[cc][6], colacc[cc][7]);
        }
    }
    __syncthreads();

    // catT[b][l][cg*16+lc]; l<64 -> x_h (row means), l>=64 -> x_w (col means)
    const float inv64 = 1.f / 64.f;
    {
        const int lc = t & 15;
#pragma unroll
        for (int r = 0; r < 8; ++r) {
            const int l = r * 16 + (t >> 4);
            const float val =
                (l < 64 ? rowsum[lc * 64 + l] : colsum[lc * 64 + (l - 64)]) * inv64;
            g_catT[((size_t)(b * 128 + l)) * NC + cg * 16 + lc] = val;
        }
    }
    // cmean partial for this cg: unpack 4 waves' slices, sum, scale by 1/256
    {
        const int u0 = t * 8;           // 8 u32 = 16 positions per thread
        float acc[16];
#pragma unroll
        for (int k = 0; k < 16; ++k) acc[k] = 0.f;
#pragma unroll
        for (int w = 0; w < 4; ++w) {
            const uint4 qa = *(const uint4*)&sliceP[w][u0];
            const uint4 qb = *(const uint4*)&sliceP[w][u0 + 4];
            const unsigned int uu[8] = {qa.x, qa.y, qa.z, qa.w, qb.x, qb.y, qb.z, qb.w};
#pragma unroll
            for (int k = 0; k < 8; ++k) {
                acc[2 * k]     += bf2f(uu[k] & 0xffffu);
                acc[2 * k + 1] += bf2f(uu[k] >> 16);
            }
        }
        const float invC = 1.f / 256.f;
        float* dst = g_cmeanp + (((size_t)(b * 16 + cg)) << 12) + t * 16;
#pragma unroll
        for (int k4 = 0; k4 < 4; ++k4)
            *(float4*)(dst + k4 * 4) = make_float4(acc[k4 * 4] * invC,
                                                   acc[k4 * 4 + 1] * invC,
                                                   acc[k4 * 4 + 2] * invC,
                                                   acc[k4 * 4 + 3] * invC);
    }
}

// ---------------------------------------------------------------------------
// Kernel B: grid (4, NB). bx = half*2 + csplit.
//   all blocks: y(half) = BN+ReLU(w10 @ cat-half), s(csplit's 128 ch).
//   bx==0: pooled -> f_ch.   bx==1: cmean reduce -> f_sa.
// ---------------------------------------------------------------------------
__global__ __launch_bounds__(256) void kB(
    const void* __restrict__ w10, const void* __restrict__ w11,
    const void* __restrict__ bn_gamma, const void* __restrict__ bn_beta,
    const void* __restrict__ bn_mean, const void* __restrict__ bn_var,
    const void* __restrict__ w20, const void* __restrict__ w21) {

    __shared__ float w10_lds[16 * 260];   // 16.25 KB, stride 260
    __shared__ float w11_lds[2048];       // this csplit's 128 rows [c][16]
    __shared__ float y_lds[16 * 65];
    __shared__ float cm[4096];            // bx==1 only
    __shared__ float pooled[260];         // bx==0 only
    __shared__ float bnA[16], bnBv[16];

    const int t  = threadIdx.x;
    const int bx = blockIdx.x;
    const int half = bx >> 1, csplit = bx & 1;
    const int b  = blockIdx.y;
    const int mode = g_mode;

    for (int j = t; j < 4096; j += 256)
        w10_lds[(j >> 8) * 260 + (j & 255)] = loadw(w10, j, mode);
    for (int j = t; j < 2048; j += 256)
        w11_lds[j] = loadw(w11, csplit * 2048 + j, mode);
    if (t < 16) {
        const float inv = rsqrtf(loadw(bn_var, t, mode) + 1e-5f) *
                          loadw(bn_gamma, t, mode);
        bnA[t]  = inv;
        bnBv[t] = loadw(bn_beta, t, mode) - loadw(bn_mean, t, mode) * inv;
    }
    __syncthreads();

    // y[m][l] for this half's 64 l-columns
    {
        const int m = t & 15, li = t >> 4;
#pragma unroll
        for (int rep = 0; rep < 4; ++rep) {
            const int l = rep * 16 + li;
            const float4* cr =
                (const float4*)(g_catT + ((size_t)(b * 128 + half * 64 + l)) * NC);
            const float4* wr = (const float4*)(w10_lds + m * 260);
            float acc = 0.f;
#pragma unroll 8
            for (int c4 = 0; c4 < 64; ++c4) {
                const float4 a = wr[c4], v = cr[c4];
                acc = fmaf(a.x, v.x, fmaf(a.y, v.y, fmaf(a.z, v.z, fmaf(a.w, v.w, acc))));
            }
            y_lds[m * 65 + l] = fmaxf(fmaf(acc, bnA[m], bnBv[m]), 0.f);  // BN+ReLU
        }
    }
    __syncthreads();

    // s = sigmoid(w11 @ y) for this csplit's 128 channels
    {
        const int h = t & 63, q = t >> 6;
        float yr[16];
#pragma unroll
        for (int mm = 0; mm < 16; ++mm) yr[mm] = y_lds[mm * 65 + h];
        float* sout = half ? g_sw : g_sh;
        const size_t sb = ((size_t)b) * NC * 64;
        for (int ci = 0; ci < 32; ++ci) {
            const int cl = q * 32 + ci;                 // local 0..127
            const float4* wrow = (const float4*)(w11_lds + cl * 16);
            const float4 w0 = wrow[0], w1 = wrow[1], w2 = wrow[2], w3 = wrow[3];
            float acc;
            acc = fmaf(w0.x, yr[0], w0.y * yr[1]);
            acc = fmaf(w0.z, yr[2], acc); acc = fmaf(w0.w, yr[3], acc);
            acc = fmaf(w1.x, yr[4], acc); acc = fmaf(w1.y, yr[5], acc);
            acc = fmaf(w1.z, yr[6], acc); acc = fmaf(w1.w, yr[7], acc);
            acc = fmaf(w2.x, yr[8], acc); acc = fmaf(w2.y, yr[9], acc);
            acc = fmaf(w2.z, yr[10], acc); acc = fmaf(w2.w, yr[11], acc);
            acc = fmaf(w3.x, yr[12], acc); acc = fmaf(w3.y, yr[13], acc);
            acc = fmaf(w3.z, yr[14], acc); acc = fmaf(w3.w, yr[15], acc);
            sout[sb + (size_t)(csplit * 128 + cl) * 64 + h] = sigmoidf_(acc);
        }
    }

    if (bx == 0) {
        // pooled over h of x_h, then conv1d K=5 SAME -> f_ch
        float p = 0.f;
        for (int l = 0; l < 64; ++l)
            p += g_catT[((size_t)(b * 128 + l)) * NC + t];
        pooled[2 + t] = p * (1.f / 64.f);
        if (t < 2) { pooled[t] = 0.f; pooled[258 + t] = 0.f; }
        __syncthreads();
        float w20f[5];
#pragma unroll
        for (int k = 0; k < 5; ++k) w20f[k] = loadw(w20, k, mode);
        float acc = 0.f;
#pragma unroll
        for (int k = 0; k < 5; ++k) acc = fmaf(w20f[k], pooled[t + k], acc);
        g_fch[b * NC + t] = acc;
    } else if (bx == 1) {
        // reduce 16 cmean partials -> cm, then conv3x3 SAME + sigmoid -> f_sa
#pragma unroll
        for (int it = 0; it < 4; ++it) {
            const int j = it * 1024 + t * 4;
            float4 s = make_float4(0.f, 0.f, 0.f, 0.f);
            for (int gcg = 0; gcg < 16; ++gcg) {
                const float4 v =
                    *(const float4*)&g_cmeanp[(((size_t)(b * 16 + gcg)) << 12) + j];
                s.x += v.x; s.y += v.y; s.z += v.z; s.w += v.w;
            }
            *(float4*)&cm[j] = s;
        }
        __syncthreads();
        float w21f[9];
#pragma unroll
        for (int k = 0; k < 9; ++k) w21f[k] = loadw(w21, k, mode);
        for (int r = 0; r < 16; ++r) {
            const int j = r * 256 + t;
            const int hh = j >> 6, ww = j & 63;
            float acc = 0.f;
#pragma unroll
            for (int dy = 0; dy < 3; ++dy) {
                const int hy = hh + dy - 1;
                if (hy < 0 || hy > 63) continue;
#pragma unroll
                for (int dx = 0; dx < 3; ++dx) {
                    const int wx = ww + dx - 1;
                    if (wx < 0 || wx > 63) continue;
                    acc = fmaf(w21f[dy * 3 + dx], cm[hy * 64 + wx], acc);
                }
            }
            g_fsa[b * 4096 + j] = sigmoidf_(acc);
        }
    }
}

// ---------------------------------------------------------------------------
// Kernel C: out = x * (f_ch + s_h*s_w + f_sa), 8 elements per thread.
// (Verbatim structure from the passing round-3 kernel.)
// ---------------------------------------------------------------------------
__global__ __launch_bounds__(256) void kC(const void* __restrict__ x,
                                          void* __restrict__ out) {
    const unsigned e = blockIdx.x * 256 + threadIdx.x;   // < 2^22
    const int w0 = (e & 7) << 3;
    const int h  = (e >> 3) & 63;
    const int c  = (e >> 9) & 255;
    const int b  = e >> 17;
    const int mode = g_mode;

    float v[8];
    loadx8(x, e, mode, v);

    const float fc = g_fch[b * NC + c];
    const float sh = g_sh[((size_t)(b * NC + c)) * 64 + h];
    const float* swp = g_sw + ((size_t)(b * NC + c)) * 64 + w0;
    const float* fsp = g_fsa + (size_t)b * 4096 + h * 64 + w0;
    const float4 swa = *(const float4*)(swp);
    const float4 swb = *(const float4*)(swp + 4);
    const float4 fsa = *(const float4*)(fsp);
    const float4 fsb = *(const float4*)(fsp + 4);

    float r[8];
    r[0] = v[0] * (fc + sh * swa.x + fsa.x);
    r[1] = v[1] * (fc + sh * swa.y + fsa.y);
    r[2] = v[2] * (fc + sh * swa.z + fsa.z);
    r[3] = v[3] * (fc + sh * swa.w + fsa.w);
    r[4] = v[4] * (fc + sh * swb.x + fsb.x);
    r[5] = v[5] * (fc + sh * swb.y + fsb.y);
    r[6] = v[6] * (fc + sh * swb.z + fsb.z);
    r[7] = v[7] * (fc + sh * swb.w + fsb.w);

    store8(out, e, mode, r);
}

extern "C" void kernel_launch(void* const* d_in, const int* in_sizes, int n_in,
                              void* d_out, int out_size, void* d_ws, size_t ws_size,
                              hipStream_t stream) {
    const void* x        = d_in[0];
    const void* w10      = d_in[1];
    const void* w11      = d_in[2];
    const void* bn_gamma = d_in[3];
    const void* bn_beta  = d_in[4];
    const void* bn_mean  = d_in[5];
    const void* bn_var   = d_in[6];
    const void* w20      = d_in[7];
    const void* w21      = d_in[8];

    kSniff<<<1, 256, 0, stream>>>((const u16*)x);
    kA<<<dim3(16, NB), 256, 0, stream>>>(x);
    kB<<<dim3(4, NB), 256, 0, stream>>>(w10, w11, bn_gamma, bn_beta,
                                        bn_mean, bn_var, w20, w21);
    kC<<<(NB * NC * NH * NW / 8) / 256, 256, 0, stream>>>(x, d_out);
}